// Round 6
// baseline (1112.956 us; speedup 1.0000x reference)
//
#include <hip/hip_runtime.h>
#include <math.h>

#define T_TOK 8192
#define H_DIM 1024
#define F_DIM 4096
#define N_EXP 8
#define PAIR_CAP 16512

#define GBM 256
#define GBN 256
#define BK 32
#define DEPTH 3   // staging ring depth; vmcnt wait = 4*(DEPTH-1) = 8

typedef __attribute__((ext_vector_type(8))) short short8;
typedef __attribute__((ext_vector_type(4))) float floatx4;
typedef unsigned int u32;

// Pre-transposed bf16 weights (rebuilt every launch)
__device__ unsigned short g_w1t[(size_t)N_EXP * F_DIM * H_DIM];  // [E][F][H] k-contig
__device__ unsigned short g_w2t[(size_t)N_EXP * H_DIM * F_DIM];  // [E][H][F] k-contig

// workspace layout (bytes)
#define XB_OFF   0ull
#define HID_OFF  16777216ull
#define PTOK_OFF 152043520ull
#define PW_OFF   152109568ull
#define TOPI_OFF 152175616ull
#define TOPW_OFF 152241152ull
#define CNT_OFF  152306688ull
#define BASE_OFF 152306720ull
#define CUR_OFF  152306752ull
#define WS_NEED  152306784ull

__device__ __forceinline__ unsigned short f2bf(float f) {
  union { float f; unsigned u; } v; v.f = f;
  unsigned r = v.u + 0x7FFFu + ((v.u >> 16) & 1u);   // RNE
  return (unsigned short)(r >> 16);
}

__device__ __forceinline__ void async16(const void* g, void* l) {
  __builtin_amdgcn_global_load_lds(
      (const __attribute__((address_space(1))) u32*)g,
      (__attribute__((address_space(3))) u32*)l, 16, 0, 0);
}

// ---------------- weight transpose+cast: W[K][N] fp32 -> Wt[N][K] bf16 ----------------
__global__ __launch_bounds__(256) void wt_kernel(const float* __restrict__ W,
                                                 int K, int N, int which) {
  unsigned short* Wt = which ? g_w2t : g_w1t;
  int e = blockIdx.z;
  int kt = blockIdx.y;
  int ntt = blockIdx.x;
  __shared__ float tile[64][65];
  const float* Wp = W + (size_t)e * K * N + (size_t)(kt * 64) * N + ntt * 64;
  int t = threadIdx.x;
  int tr = t >> 4;
  int tc = (t & 15) * 4;
#pragma unroll
  for (int i = 0; i < 4; i++) {
    int row = tr + i * 16;
    float4 v = *(const float4*)(Wp + (size_t)row * N + tc);
    tile[row][tc] = v.x; tile[row][tc + 1] = v.y;
    tile[row][tc + 2] = v.z; tile[row][tc + 3] = v.w;
  }
  __syncthreads();
  unsigned short* Wo = Wt + (size_t)e * K * N + (size_t)(ntt * 64) * K + kt * 64;
  int on = t >> 2;
  int ok = (t & 3) * 16;
  unsigned short __attribute__((aligned(16))) buf[16];
#pragma unroll
  for (int i = 0; i < 16; i++) buf[i] = f2bf(tile[ok + i][on]);
  *(uint4*)(Wo + (size_t)on * K + ok) = ((uint4*)buf)[0];
  *(uint4*)(Wo + (size_t)on * K + ok + 8) = ((uint4*)buf)[1];
}

// ---------------- router: logits, softmax, top-2, bf16(x) — no atomics ----------------
__global__ __launch_bounds__(256) void router_kernel(
    const float* __restrict__ x, const float* __restrict__ rw,
    unsigned short* __restrict__ xb, int* __restrict__ topi,
    float* __restrict__ topw) {
  __shared__ float srw[N_EXP * H_DIM];
  int tid = threadIdx.x;
#pragma unroll
  for (int i = 0; i < 8; i++) {
    int v4 = tid + i * 256;
    ((float4*)srw)[v4] = ((const float4*)rw)[v4];
  }
  __syncthreads();
  int wave = tid >> 6, lane = tid & 63;
  int t = blockIdx.x * 4 + wave;
  const float* xrow = x + (size_t)t * H_DIM;
  unsigned short* xbrow = xb + (size_t)t * H_DIM;
  float acc[N_EXP];
#pragma unroll
  for (int e = 0; e < N_EXP; e++) acc[e] = 0.f;
#pragma unroll
  for (int j = 0; j < 4; j++) {
    int v4 = j * 64 + lane;
    float4 xv = ((const float4*)xrow)[v4];
    ushort4 bv;
    bv.x = f2bf(xv.x); bv.y = f2bf(xv.y); bv.z = f2bf(xv.z); bv.w = f2bf(xv.w);
    ((ushort4*)xbrow)[v4] = bv;
#pragma unroll
    for (int e = 0; e < N_EXP; e++) {
      float4 rv = ((const float4*)(srw + e * H_DIM))[v4];
      acc[e] += xv.x * rv.x + xv.y * rv.y + xv.z * rv.z + xv.w * rv.w;
    }
  }
#pragma unroll
  for (int e = 0; e < N_EXP; e++)
#pragma unroll
    for (int off = 32; off > 0; off >>= 1)
      acc[e] += __shfl_xor(acc[e], off);
  float mx = acc[0];
#pragma unroll
  for (int e = 1; e < N_EXP; e++) mx = fmaxf(mx, acc[e]);
  float p[N_EXP], s = 0.f;
#pragma unroll
  for (int e = 0; e < N_EXP; e++) { p[e] = __expf(acc[e] - mx); s += p[e]; }
  float inv = 1.f / s;
  int i1 = 0; float p1 = p[0];
#pragma unroll
  for (int e = 1; e < N_EXP; e++) if (p[e] > p1) { p1 = p[e]; i1 = e; }
  int i2 = -1; float p2 = -1.f;
#pragma unroll
  for (int e = 0; e < N_EXP; e++) if (e != i1 && p[e] > p2) { p2 = p[e]; i2 = e; }
  if (lane == 0) {
    topi[t * 2] = i1;     topw[t * 2] = p1 * inv;
    topi[t * 2 + 1] = i2; topw[t * 2 + 1] = p2 * inv;
  }
}

// ---------------- histogram: LDS-privatized counts ----------------
__global__ __launch_bounds__(256) void hist_kernel(const int* __restrict__ topi,
                                                   int* __restrict__ counts) {
  __shared__ int h[N_EXP];
  int tid = threadIdx.x;
  if (tid < N_EXP) h[tid] = 0;
  __syncthreads();
  int i = blockIdx.x * 256 + tid;   // grid 64 covers 16384 picks
  atomicAdd(&h[topi[i]], 1);        // LDS atomic (per-CU, fast)
  __syncthreads();
  if (tid < N_EXP) atomicAdd(&counts[tid], h[tid]);
}

__global__ void scan_kernel(const int* __restrict__ counts,
                            int* __restrict__ base, int* __restrict__ cursor) {
  if (threadIdx.x == 0) {
    int s = 0;
    for (int e = 0; e < N_EXP; e++) { base[e] = s; cursor[e] = s; s += counts[e]; }
  }
}

// ---------------- build: two-level (LDS cursors + 8 global atomics/block) ----------------
__global__ __launch_bounds__(256) void build_kernel(
    const int* __restrict__ topi, const float* __restrict__ topw,
    int* __restrict__ cursor, int* __restrict__ ptok, float* __restrict__ pw) {
  __shared__ int lcnt[N_EXP], lbase[N_EXP], lcur[N_EXP];
  int tid = threadIdx.x;
  if (tid < N_EXP) { lcnt[tid] = 0; lcur[tid] = 0; }
  __syncthreads();
  int t = blockIdx.x * 256 + tid;
  int e0 = topi[t * 2], e1 = topi[t * 2 + 1];
  atomicAdd(&lcnt[e0], 1);
  atomicAdd(&lcnt[e1], 1);
  __syncthreads();
  if (tid < N_EXP) lbase[tid] = atomicAdd(&cursor[tid], lcnt[tid]);
  __syncthreads();
  int o0 = atomicAdd(&lcur[e0], 1);
  int o1 = atomicAdd(&lcur[e1], 1);
  int s0 = lbase[e0] + o0, s1 = lbase[e1] + o1;
  ptok[s0] = t; pw[s0] = topw[t * 2];
  ptok[s1] = t; pw[s1] = topw[t * 2 + 1];
}

// ---------------- GEMM1: hid = gelu(Xg @ w1t^T + b1) ----------------
// 256x256 tile, 512 threads (8 waves, 2x4). XCD i owns expert i (bijective
// chunked swizzle); within an expert nt-major/mt-minor so the B strip
// (512 KB) stays hot in the XCD's L2. Staging: DEPTH=3 ring of
// global_load_lds with source-side k-quad XOR (linear LDS dest, swizzled
// read — both-sides involution), counted vmcnt(8), dual raw barriers.
// 128 FLOP per staged byte (2x the 128^2 tile).
__global__ __launch_bounds__(512, 2) void gemm1_kernel(
    const unsigned short* __restrict__ xb, const float* __restrict__ b1,
    unsigned short* __restrict__ hid, const int* __restrict__ ptok,
    const int* __restrict__ counts, const int* __restrict__ base) {
  int f = blockIdx.x;
  int w = (f & 7) * 512 + (f >> 3);   // bijective: 4096 = 8 * 512
  int e  = w >> 9;                    // 512 works per expert
  int w2 = w & 511;
  int nt = w2 >> 5;                   // 16 nt (nt-major)
  int mt = w2 & 31;                   // 32 mt (mt-minor)
  int cnt = counts[e];
  if (mt * GBM >= cnt) return;
  int rbase = base[e] + mt * GBM;

  __shared__ unsigned short sA[DEPTH * GBM * BK];  // 3 x 16 KB
  __shared__ unsigned short sB[DEPTH * GBN * BK];  // 3 x 16 KB

  int tid = threadIdx.x;
  int wv = tid >> 6, lane = tid & 63;

  int r0 = tid >> 2;        // rows 0..127
  int r1 = r0 + 128;        // rows 128..255
  int kq0 = (tid & 3) ^ ((r0 >> 1) & 3);
  int kq1 = (tid & 3) ^ ((r1 >> 1) & 3);

  int tok0 = (mt * GBM + r0 < cnt) ? ptok[rbase + r0] : 0;
  int tok1 = (mt * GBM + r1 < cnt) ? ptok[rbase + r1] : 0;
  const unsigned short* aP0 = xb + (size_t)tok0 * H_DIM + kq0 * 8;
  const unsigned short* aP1 = xb + (size_t)tok1 * H_DIM + kq1 * 8;
  const unsigned short* wb = g_w1t + (size_t)e * F_DIM * H_DIM + (size_t)nt * GBN * H_DIM;
  const unsigned short* bP0 = wb + (size_t)r0 * H_DIM + kq0 * 8;
  const unsigned short* bP1 = wb + (size_t)r1 * H_DIM + kq1 * 8;

  char* sAb = (char*)sA + wv * 1024;   // round r0 dest; +8192 for r1; +16384*buf
  char* sBb = (char*)sB + wv * 1024;

  int wr = wv >> 2, wc = wv & 3;
  int wm = wr * 128, wn = wc * 64;
  int lm = lane & 15, quad = lane >> 4;
  const unsigned short* aRd[8];
  const unsigned short* bRd[4];
#pragma unroll
  for (int mi = 0; mi < 8; mi++) {
    int R = wm + mi * 16 + lm;
    aRd[mi] = sA + (size_t)(4 * R + (quad ^ ((R >> 1) & 3))) * 8;
  }
#pragma unroll
  for (int ni = 0; ni < 4; ni++) {
    int R = wn + ni * 16 + lm;
    bRd[ni] = sB + (size_t)(4 * R + (quad ^ ((R >> 1) & 3))) * 8;
  }

  floatx4 acc[8][4];
#pragma unroll
  for (int mi = 0; mi < 8; mi++)
#pragma unroll
    for (int ni = 0; ni < 4; ni++)
      acc[mi][ni] = (floatx4){0.f, 0.f, 0.f, 0.f};

  // prologue: prefetch tiles 0..DEPTH-1 (4 loads/thread each)
#pragma unroll
  for (int d = 0; d < DEPTH; d++) {
    async16(aP0, sAb + d * 16384);        async16(aP1, sAb + d * 16384 + 8192);
    async16(bP0, sBb + d * 16384);        async16(bP1, sBb + d * 16384 + 8192);
    aP0 += BK; aP1 += BK; bP0 += BK; bP1 += BK;
  }

  const int niter = H_DIM / BK;   // 32
  int bufc = 0;
  for (int i = 0; i < niter; i++) {
    // tile i's 4 loads are the oldest; keep the younger 8 in flight
    asm volatile("s_waitcnt vmcnt(8)" ::: "memory");
    __builtin_amdgcn_sched_barrier(0);
    __builtin_amdgcn_s_barrier();            // B1: tile i ready everywhere
    __builtin_amdgcn_sched_barrier(0);

    int co = bufc * (GBM * BK);   // shorts: 8192 per buffer
    short8 af[8], bfr[4];
#pragma unroll
    for (int mi = 0; mi < 8; mi++) af[mi] = *(const short8*)(aRd[mi] + co);
#pragma unroll
    for (int ni = 0; ni < 4; ni++) bfr[ni] = *(const short8*)(bRd[ni] + co);

    asm volatile("s_waitcnt lgkmcnt(0)" ::: "memory");
    __builtin_amdgcn_sched_barrier(0);
    __builtin_amdgcn_s_barrier();            // B2: tile i consumed everywhere
    __builtin_amdgcn_sched_barrier(0);

    // refill buf[bufc] with tile i+DEPTH (tail clamps pointer: constant
    // issue count keeps per-wave vmcnt bookkeeping fixed)
    async16(aP0, sAb + bufc * 16384);        async16(aP1, sAb + bufc * 16384 + 8192);
    async16(bP0, sBb + bufc * 16384);        async16(bP1, sBb + bufc * 16384 + 8192);
    if (i + DEPTH < niter - 1) { aP0 += BK; aP1 += BK; bP0 += BK; bP1 += BK; }

    __builtin_amdgcn_s_setprio(1);
#pragma unroll
    for (int mi = 0; mi < 8; mi++)
#pragma unroll
      for (int ni = 0; ni < 4; ni++)
        acc[mi][ni] = __builtin_amdgcn_mfma_f32_16x16x32_bf16(
            af[mi], bfr[ni], acc[mi][ni], 0, 0, 0);
    __builtin_amdgcn_s_setprio(0);

    bufc = (bufc == DEPTH - 1) ? 0 : bufc + 1;
  }
  // drain tail prefetches before LDS can be reassigned to the next block
  asm volatile("s_waitcnt vmcnt(0)" ::: "memory");

  const float* b1e = b1 + (size_t)e * F_DIM;
#pragma unroll
  for (int mi = 0; mi < 8; mi++) {
#pragma unroll
    for (int r = 0; r < 4; r++) {
      int row = wm + mi * 16 + quad * 4 + r;
      if (mt * GBM + row < cnt) {
        size_t hrow = (size_t)(rbase + row) * F_DIM;
#pragma unroll
        for (int ni = 0; ni < 4; ni++) {
          int col = nt * GBN + wn + ni * 16 + lm;
          float v = acc[mi][ni][r] + b1e[col];
          v = 0.5f * v * (1.f + erff(v * 0.70710678118f));
          hid[hrow + col] = f2bf(v);
        }
      }
    }
  }
}

// ---------------- GEMM2: out[tok] += w * (hid @ w2t^T + b2) ----------------
// 256x256 tile; within an expert mt-major/nt-minor so the A panel (2 MB)
// is shared by the 4 nt-blocks. A-row staging clamped to base[e] for pad
// rows (BM=256 can overrun the 16512-row hid cap otherwise).
__global__ __launch_bounds__(512, 2) void gemm2_kernel(
    const unsigned short* __restrict__ hid, const float* __restrict__ b2,
    const int* __restrict__ ptok, const float* __restrict__ pwt,
    const int* __restrict__ counts, const int* __restrict__ base,
    float* __restrict__ out) {
  int f = blockIdx.x;
  int w = (f & 7) * 128 + (f >> 3);   // bijective: 1024 = 8 * 128
  int e  = w >> 7;                    // 128 works per expert
  int w2 = w & 127;
  int mt = w2 >> 2;                   // 32 mt (mt-major)
  int nt = w2 & 3;                    // 4 nt (nt-minor)
  int cnt = counts[e];
  if (mt * GBM >= cnt) return;
  int rbase = base[e] + mt * GBM;

  __shared__ unsigned short sA[DEPTH * GBM * BK];
  __shared__ unsigned short sB[DEPTH * GBN * BK];

  int tid = threadIdx.x;
  int wv = tid >> 6, lane = tid & 63;

  int r0 = tid >> 2;
  int r1 = r0 + 128;
  int kq0 = (tid & 3) ^ ((r0 >> 1) & 3);
  int kq1 = (tid & 3) ^ ((r1 >> 1) & 3);

  int ar0 = (mt * GBM + r0 < cnt) ? (rbase + r0) : base[e];  // clamp: stay in hid
  int ar1 = (mt * GBM + r1 < cnt) ? (rbase + r1) : base[e];
  const unsigned short* aP0 = hid + (size_t)ar0 * F_DIM + kq0 * 8;
  const unsigned short* aP1 = hid + (size_t)ar1 * F_DIM + kq1 * 8;
  const unsigned short* wb = g_w2t + (size_t)e * H_DIM * F_DIM + (size_t)nt * GBN * F_DIM;
  const unsigned short* bP0 = wb + (size_t)r0 * F_DIM + kq0 * 8;
  const unsigned short* bP1 = wb + (size_t)r1 * F_DIM + kq1 * 8;

  char* sAb = (char*)sA + wv * 1024;
  char* sBb = (char*)sB + wv * 1024;

  int wr = wv >> 2, wc = wv & 3;
  int wm = wr * 128, wn = wc * 64;
  int lm = lane & 15, quad = lane >> 4;
  const unsigned short* aRd[8];
  const unsigned short* bRd[4];
#pragma unroll
  for (int mi = 0; mi < 8; mi++) {
    int R = wm + mi * 16 + lm;
    aRd[mi] = sA + (size_t)(4 * R + (quad ^ ((R >> 1) & 3))) * 8;
  }
#pragma unroll
  for (int ni = 0; ni < 4; ni++) {
    int R = wn + ni * 16 + lm;
    bRd[ni] = sB + (size_t)(4 * R + (quad ^ ((R >> 1) & 3))) * 8;
  }

  floatx4 acc[8][4];
#pragma unroll
  for (int mi = 0; mi < 8; mi++)
#pragma unroll
    for (int ni = 0; ni < 4; ni++)
      acc[mi][ni] = (floatx4){0.f, 0.f, 0.f, 0.f};

#pragma unroll
  for (int d = 0; d < DEPTH; d++) {
    async16(aP0, sAb + d * 16384);        async16(aP1, sAb + d * 16384 + 8192);
    async16(bP0, sBb + d * 16384);        async16(bP1, sBb + d * 16384 + 8192);
    aP0 += BK; aP1 += BK; bP0 += BK; bP1 += BK;
  }

  const int niter = F_DIM / BK;   // 128
  int bufc = 0;
  for (int i = 0; i < niter; i++) {
    asm volatile("s_waitcnt vmcnt(8)" ::: "memory");
    __builtin_amdgcn_sched_barrier(0);
    __builtin_amdgcn_s_barrier();            // B1: tile i ready
    __builtin_amdgcn_sched_barrier(0);

    int co = bufc * (GBM * BK);
    short8 af[8], bfr[4];
#pragma unroll
    for (int mi = 0; mi < 8; mi++) af[mi] = *(const short8*)(aRd[mi] + co);
#pragma unroll
    for (int ni = 0; ni < 4; ni++) bfr[ni] = *(const short8*)(bRd[ni] + co);

    asm volatile("s_waitcnt lgkmcnt(0)" ::: "memory");
    __builtin_amdgcn_sched_barrier(0);
    __builtin_amdgcn_s_barrier();            // B2: tile i consumed
    __builtin_amdgcn_sched_barrier(0);

    async16(aP0, sAb + bufc * 16384);        async16(aP1, sAb + bufc * 16384 + 8192);
    async16(bP0, sBb + bufc * 16384);        async16(bP1, sBb + bufc * 16384 + 8192);
    if (i + DEPTH < niter - 1) { aP0 += BK; aP1 += BK; bP0 += BK; bP1 += BK; }

    __builtin_amdgcn_s_setprio(1);
#pragma unroll
    for (int mi = 0; mi < 8; mi++)
#pragma unroll
      for (int ni = 0; ni < 4; ni++)
        acc[mi][ni] = __builtin_amdgcn_mfma_f32_16x16x32_bf16(
            af[mi], bfr[ni], acc[mi][ni], 0, 0, 0);
    __builtin_amdgcn_s_setprio(0);

    bufc = (bufc == DEPTH - 1) ? 0 : bufc + 1;
  }
  asm volatile("s_waitcnt vmcnt(0)" ::: "memory");

  const float* b2e = b2 + (size_t)e * H_DIM;
#pragma unroll
  for (int mi = 0; mi < 8; mi++) {
#pragma unroll
    for (int r = 0; r < 4; r++) {
      int row = wm + mi * 16 + quad * 4 + r;
      if (mt * GBM + row < cnt) {
        int prow = rbase + row;
        int tok = ptok[prow];
        float pw = pwt[prow];
        float* orow = out + (size_t)tok * H_DIM;
#pragma unroll
        for (int ni = 0; ni < 4; ni++) {
          int col = nt * GBN + wn + ni * 16 + lm;
          atomicAdd(&orow[col], (acc[mi][ni][r] + b2e[col]) * pw);
        }
      }
    }
  }
}

extern "C" void kernel_launch(void* const* d_in, const int* in_sizes, int n_in,
                              void* d_out, int out_size, void* d_ws, size_t ws_size,
                              hipStream_t stream) {
  const float* x  = (const float*)d_in[0];
  const float* rw = (const float*)d_in[1];
  const float* w1 = (const float*)d_in[2];
  const float* b1 = (const float*)d_in[3];
  const float* w2 = (const float*)d_in[4];
  const float* b2 = (const float*)d_in[5];
  float* out = (float*)d_out;
  char* ws = (char*)d_ws;

  hipMemsetAsync(out, 0, (size_t)T_TOK * H_DIM * sizeof(float), stream);
  if (ws_size < WS_NEED) return;

  unsigned short* xb  = (unsigned short*)(ws + XB_OFF);
  unsigned short* hid = (unsigned short*)(ws + HID_OFF);
  int*   ptok   = (int*)(ws + PTOK_OFF);
  float* pw     = (float*)(ws + PW_OFF);
  int*   topi   = (int*)(ws + TOPI_OFF);
  float* topw   = (float*)(ws + TOPW_OFF);
  int*   counts = (int*)(ws + CNT_OFF);
  int*   base   = (int*)(ws + BASE_OFF);
  int*   cursor = (int*)(ws + CUR_OFF);

  hipMemsetAsync(ws + CNT_OFF, 0, 96, stream);

  wt_kernel<<<dim3(F_DIM / 64, H_DIM / 64, N_EXP), 256, 0, stream>>>(w1, H_DIM, F_DIM, 0);
  wt_kernel<<<dim3(H_DIM / 64, F_DIM / 64, N_EXP), 256, 0, stream>>>(w2, F_DIM, H_DIM, 1);
  router_kernel<<<T_TOK / 4, 256, 0, stream>>>(x, rw, xb, topi, topw);
  hist_kernel<<<64, 256, 0, stream>>>(topi, counts);
  scan_kernel<<<1, 64, 0, stream>>>(counts, base, cursor);
  build_kernel<<<T_TOK / 256, 256, 0, stream>>>(topi, topw, cursor, ptok, pw);
  gemm1_kernel<<<4096, 512, 0, stream>>>(xb, b1, hid, ptok, counts, base);
  gemm2_kernel<<<1024, 512, 0, stream>>>(hid, b2, ptok, pw, counts, base, out);
}

// Round 7
// 916.027 us; speedup vs baseline: 1.2150x; 1.2150x over previous
//
#include <hip/hip_runtime.h>
#include <math.h>

#define T_TOK 8192
#define H_DIM 1024
#define F_DIM 4096
#define N_EXP 8
#define PAIR_CAP 16512

#define BM 128
#define BN 128
#define BK 32
#define DEPTH 2   // staging ring depth; vmcnt wait = 4*(DEPTH-1)

typedef __attribute__((ext_vector_type(8))) short short8;
typedef __attribute__((ext_vector_type(4))) float floatx4;
typedef unsigned int u32;

// Pre-transposed bf16 weights (rebuilt every launch)
__device__ unsigned short g_w1t[(size_t)N_EXP * F_DIM * H_DIM];  // [E][F][H] k-contig
__device__ unsigned short g_w2t[(size_t)N_EXP * H_DIM * F_DIM];  // [E][H][F] k-contig

// workspace layout (bytes)
#define XB_OFF   0ull
#define HID_OFF  16777216ull
#define PTOK_OFF 152043520ull
#define PW_OFF   152109568ull
#define TOPI_OFF 152175616ull
#define TOPW_OFF 152241152ull
#define CNT_OFF  152306688ull
#define BASE_OFF 152306720ull
#define CUR_OFF  152306752ull
#define WS_NEED  152306784ull

__device__ __forceinline__ unsigned short f2bf(float f) {
  union { float f; unsigned u; } v; v.f = f;
  unsigned r = v.u + 0x7FFFu + ((v.u >> 16) & 1u);   // RNE
  return (unsigned short)(r >> 16);
}

__device__ __forceinline__ void async16(const void* g, void* l) {
  __builtin_amdgcn_global_load_lds(
      (const __attribute__((address_space(1))) u32*)g,
      (__attribute__((address_space(3))) u32*)l, 16, 0, 0);
}

// ---------------- weight transpose+cast: W[K][N] fp32 -> Wt[N][K] bf16 ----------------
__global__ __launch_bounds__(256) void wt_kernel(const float* __restrict__ W,
                                                 int K, int N, int which) {
  unsigned short* Wt = which ? g_w2t : g_w1t;
  int e = blockIdx.z;
  int kt = blockIdx.y;
  int ntt = blockIdx.x;
  __shared__ float tile[64][65];
  const float* Wp = W + (size_t)e * K * N + (size_t)(kt * 64) * N + ntt * 64;
  int t = threadIdx.x;
  int tr = t >> 4;
  int tc = (t & 15) * 4;
#pragma unroll
  for (int i = 0; i < 4; i++) {
    int row = tr + i * 16;
    float4 v = *(const float4*)(Wp + (size_t)row * N + tc);
    tile[row][tc] = v.x; tile[row][tc + 1] = v.y;
    tile[row][tc + 2] = v.z; tile[row][tc + 3] = v.w;
  }
  __syncthreads();
  unsigned short* Wo = Wt + (size_t)e * K * N + (size_t)(ntt * 64) * K + kt * 64;
  int on = t >> 2;
  int ok = (t & 3) * 16;
  unsigned short __attribute__((aligned(16))) buf[16];
#pragma unroll
  for (int i = 0; i < 16; i++) buf[i] = f2bf(tile[ok + i][on]);
  *(uint4*)(Wo + (size_t)on * K + ok) = ((uint4*)buf)[0];
  *(uint4*)(Wo + (size_t)on * K + ok + 8) = ((uint4*)buf)[1];
}

// ---------------- router: logits, softmax, top-2, bf16(x) — no atomics ----------------
__global__ __launch_bounds__(256) void router_kernel(
    const float* __restrict__ x, const float* __restrict__ rw,
    unsigned short* __restrict__ xb, int* __restrict__ topi,
    float* __restrict__ topw) {
  __shared__ float srw[N_EXP * H_DIM];
  int tid = threadIdx.x;
#pragma unroll
  for (int i = 0; i < 8; i++) {
    int v4 = tid + i * 256;
    ((float4*)srw)[v4] = ((const float4*)rw)[v4];
  }
  __syncthreads();
  int wave = tid >> 6, lane = tid & 63;
  int t = blockIdx.x * 4 + wave;
  const float* xrow = x + (size_t)t * H_DIM;
  unsigned short* xbrow = xb + (size_t)t * H_DIM;
  float acc[N_EXP];
#pragma unroll
  for (int e = 0; e < N_EXP; e++) acc[e] = 0.f;
#pragma unroll
  for (int j = 0; j < 4; j++) {
    int v4 = j * 64 + lane;
    float4 xv = ((const float4*)xrow)[v4];
    ushort4 bv;
    bv.x = f2bf(xv.x); bv.y = f2bf(xv.y); bv.z = f2bf(xv.z); bv.w = f2bf(xv.w);
    ((ushort4*)xbrow)[v4] = bv;
#pragma unroll
    for (int e = 0; e < N_EXP; e++) {
      float4 rv = ((const float4*)(srw + e * H_DIM))[v4];
      acc[e] += xv.x * rv.x + xv.y * rv.y + xv.z * rv.z + xv.w * rv.w;
    }
  }
#pragma unroll
  for (int e = 0; e < N_EXP; e++)
#pragma unroll
    for (int off = 32; off > 0; off >>= 1)
      acc[e] += __shfl_xor(acc[e], off);
  float mx = acc[0];
#pragma unroll
  for (int e = 1; e < N_EXP; e++) mx = fmaxf(mx, acc[e]);
  float p[N_EXP], s = 0.f;
#pragma unroll
  for (int e = 0; e < N_EXP; e++) { p[e] = __expf(acc[e] - mx); s += p[e]; }
  float inv = 1.f / s;
  int i1 = 0; float p1 = p[0];
#pragma unroll
  for (int e = 1; e < N_EXP; e++) if (p[e] > p1) { p1 = p[e]; i1 = e; }
  int i2 = -1; float p2 = -1.f;
#pragma unroll
  for (int e = 0; e < N_EXP; e++) if (e != i1 && p[e] > p2) { p2 = p[e]; i2 = e; }
  if (lane == 0) {
    topi[t * 2] = i1;     topw[t * 2] = p1 * inv;
    topi[t * 2 + 1] = i2; topw[t * 2 + 1] = p2 * inv;
  }
}

// ---------------- histogram: LDS-privatized counts ----------------
__global__ __launch_bounds__(256) void hist_kernel(const int* __restrict__ topi,
                                                   int* __restrict__ counts) {
  __shared__ int h[N_EXP];
  int tid = threadIdx.x;
  if (tid < N_EXP) h[tid] = 0;
  __syncthreads();
  int i = blockIdx.x * 256 + tid;   // grid 64 covers 16384 picks
  atomicAdd(&h[topi[i]], 1);        // LDS atomic (per-CU, fast)
  __syncthreads();
  if (tid < N_EXP) atomicAdd(&counts[tid], h[tid]);
}

__global__ void scan_kernel(const int* __restrict__ counts,
                            int* __restrict__ base, int* __restrict__ cursor) {
  if (threadIdx.x == 0) {
    int s = 0;
    for (int e = 0; e < N_EXP; e++) { base[e] = s; cursor[e] = s; s += counts[e]; }
  }
}

// ---------------- build: two-level (LDS cursors + 8 global atomics/block) ----------------
__global__ __launch_bounds__(256) void build_kernel(
    const int* __restrict__ topi, const float* __restrict__ topw,
    int* __restrict__ cursor, int* __restrict__ ptok, float* __restrict__ pw) {
  __shared__ int lcnt[N_EXP], lbase[N_EXP], lcur[N_EXP];
  int tid = threadIdx.x;
  if (tid < N_EXP) { lcnt[tid] = 0; lcur[tid] = 0; }
  __syncthreads();
  int t = blockIdx.x * 256 + tid;
  int e0 = topi[t * 2], e1 = topi[t * 2 + 1];
  atomicAdd(&lcnt[e0], 1);
  atomicAdd(&lcnt[e1], 1);
  __syncthreads();
  if (tid < N_EXP) lbase[tid] = atomicAdd(&cursor[tid], lcnt[tid]);
  __syncthreads();
  int o0 = atomicAdd(&lcur[e0], 1);
  int o1 = atomicAdd(&lcur[e1], 1);
  int s0 = lbase[e0] + o0, s1 = lbase[e1] + o1;
  ptok[s0] = t; pw[s0] = topw[t * 2];
  ptok[s1] = t; pw[s1] = topw[t * 2 + 1];
}

// ---------------- GEMM1: hid = gelu(Xg @ w1t^T + b1) ----------------
// Round-3 structure (128^2 tile, DEPTH=2, 4 blocks/CU) + L2-cohort grouping:
// per expert the work order is ntg(4) -> mt(64) -> ntl(8), nt = ntg*8+ntl.
// The ~128 concurrently-resident blocks on an XCD then share one ntg group:
// B-group = 8 strips x 256 KB = 2 MB (L2-resident), and the 8 same-mt blocks
// are adjacent in dispatch order so each A panel is fetched from L3 ~once per
// group. L3 traffic per XCD: ~260 MB -> ~24 MB; staging becomes L2-sourced.
__global__ __launch_bounds__(256, 4) void gemm1_kernel(
    const unsigned short* __restrict__ xb, const float* __restrict__ b1,
    unsigned short* __restrict__ hid, const int* __restrict__ ptok,
    const int* __restrict__ counts, const int* __restrict__ base) {
  int f = blockIdx.x;
  int w = (f & 7) * 2048 + (f >> 3);  // bijective: 16384 = 8 * 2048
  int e  = w >> 11;                   // 2048 works per expert
  int w2 = w & 2047;
  int ntg = w2 >> 9;                  // 4 groups of 8 nt
  int rem = w2 & 511;
  int mt  = rem >> 3;                 // 64 mt slots (mt-major within group)
  int nt  = ntg * 8 + (rem & 7);      // nt-minor within group
  int cnt = counts[e];
  if (mt * BM >= cnt) return;
  int rbase = base[e] + mt * BM;

  __shared__ unsigned short sA[DEPTH * BM * BK];  // 2 x 8 KB
  __shared__ unsigned short sB[DEPTH * BN * BK];

  int tid = threadIdx.x;
  int wv = tid >> 6, lane = tid & 63;

  int r0 = tid >> 2,         kq0 = (tid & 3) ^ ((r0 >> 1) & 3);
  int r1 = (tid + 256) >> 2, kq1 = (tid & 3) ^ ((r1 >> 1) & 3);

  int tok0 = (mt * BM + r0 < cnt) ? ptok[rbase + r0] : 0;
  int tok1 = (mt * BM + r1 < cnt) ? ptok[rbase + r1] : 0;
  const unsigned short* aP0 = xb + (size_t)tok0 * H_DIM + kq0 * 8;
  const unsigned short* aP1 = xb + (size_t)tok1 * H_DIM + kq1 * 8;
  const unsigned short* wb = g_w1t + (size_t)e * F_DIM * H_DIM + (size_t)nt * BN * H_DIM;
  const unsigned short* bP0 = wb + (size_t)r0 * H_DIM + kq0 * 8;
  const unsigned short* bP1 = wb + (size_t)r1 * H_DIM + kq1 * 8;

  char* sAb = (char*)sA + wv * 1024;
  char* sBb = (char*)sB + wv * 1024;

  int wm = (wv >> 1) * 64, wn = (wv & 1) * 64;
  int lm = lane & 15, quad = lane >> 4;
  const unsigned short* aRd[4];
  const unsigned short* bRd[4];
#pragma unroll
  for (int mi = 0; mi < 4; mi++) {
    int R = wm + mi * 16 + lm;
    aRd[mi] = sA + (size_t)(4 * R + (quad ^ ((R >> 1) & 3))) * 8;
  }
#pragma unroll
  for (int ni = 0; ni < 4; ni++) {
    int R = wn + ni * 16 + lm;
    bRd[ni] = sB + (size_t)(4 * R + (quad ^ ((R >> 1) & 3))) * 8;
  }

  floatx4 acc[4][4];
#pragma unroll
  for (int mi = 0; mi < 4; mi++)
#pragma unroll
    for (int ni = 0; ni < 4; ni++)
      acc[mi][ni] = (floatx4){0.f, 0.f, 0.f, 0.f};

  // prologue: prefetch tiles 0..DEPTH-1
#pragma unroll
  for (int d = 0; d < DEPTH; d++) {
    async16(aP0, sAb + d * 8192); async16(aP1, sAb + d * 8192 + 4096);
    async16(bP0, sBb + d * 8192); async16(bP1, sBb + d * 8192 + 4096);
    aP0 += BK; aP1 += BK; bP0 += BK; bP1 += BK;
  }

  const int niter = H_DIM / BK;
  int bufc = 0;
  for (int i = 0; i < niter; i++) {
    // tile i's 4 loads are the oldest; keep the younger 4 in flight
    asm volatile("s_waitcnt vmcnt(4)" ::: "memory");
    __builtin_amdgcn_sched_barrier(0);
    __builtin_amdgcn_s_barrier();            // B1: tile i ready everywhere
    __builtin_amdgcn_sched_barrier(0);

    int co = bufc * (BM * BK);
    short8 af[4], bfr[4];
#pragma unroll
    for (int mi = 0; mi < 4; mi++) af[mi] = *(const short8*)(aRd[mi] + co);
#pragma unroll
    for (int ni = 0; ni < 4; ni++) bfr[ni] = *(const short8*)(bRd[ni] + co);

    asm volatile("s_waitcnt lgkmcnt(0)" ::: "memory");
    __builtin_amdgcn_sched_barrier(0);
    __builtin_amdgcn_s_barrier();            // B2: tile i consumed everywhere
    __builtin_amdgcn_sched_barrier(0);

    // refill buf[bufc] with tile i+DEPTH (pointers clamped at the tail:
    // constant issue count keeps the per-wave vmcnt bookkeeping fixed)
    async16(aP0, sAb + bufc * 8192); async16(aP1, sAb + bufc * 8192 + 4096);
    async16(bP0, sBb + bufc * 8192); async16(bP1, sBb + bufc * 8192 + 4096);
    if (i + DEPTH < niter - 1) { aP0 += BK; aP1 += BK; bP0 += BK; bP1 += BK; }

    __builtin_amdgcn_s_setprio(1);
#pragma unroll
    for (int mi = 0; mi < 4; mi++)
#pragma unroll
      for (int ni = 0; ni < 4; ni++)
        acc[mi][ni] = __builtin_amdgcn_mfma_f32_16x16x32_bf16(
            af[mi], bfr[ni], acc[mi][ni], 0, 0, 0);
    __builtin_amdgcn_s_setprio(0);

    bufc ^= 1;
  }
  // drain tail prefetches before LDS can be reassigned to the next block
  asm volatile("s_waitcnt vmcnt(0)" ::: "memory");

  const float* b1e = b1 + (size_t)e * F_DIM;
#pragma unroll
  for (int mi = 0; mi < 4; mi++) {
#pragma unroll
    for (int r = 0; r < 4; r++) {
      int row = wm + mi * 16 + quad * 4 + r;
      if (mt * BM + row < cnt) {
        size_t hrow = (size_t)(rbase + row) * F_DIM;
#pragma unroll
        for (int ni = 0; ni < 4; ni++) {
          int col = nt * BN + wn + ni * 16 + lm;
          float v = acc[mi][ni][r] + b1e[col];
          v = 0.5f * v * (1.f + erff(v * 0.70710678118f));
          hid[hrow + col] = f2bf(v);
        }
      }
    }
  }
}

// ---------------- GEMM2: out[tok] += w * (hid @ w2t^T + b2) ----------------
// L2-cohort grouping: ntg(4) -> mt(64) -> ntl(2), nt = ntg*2+ntl. B-group
// = 2 strips x 1 MB L2-resident; each A panel (1 MB) fetched from L3 once
// per group (adjacent same-mt blocks), 4x total.
__global__ __launch_bounds__(256, 4) void gemm2_kernel(
    const unsigned short* __restrict__ hid, const float* __restrict__ b2,
    const int* __restrict__ ptok, const float* __restrict__ pwt,
    const int* __restrict__ counts, const int* __restrict__ base,
    float* __restrict__ out) {
  int f = blockIdx.x;
  int w = (f & 7) * 512 + (f >> 3);   // bijective: 4096 = 8 * 512
  int e  = w >> 9;                    // 512 works per expert
  int w2 = w & 511;
  int ntg = w2 >> 7;                  // 4 groups of 2 nt
  int rem = w2 & 127;
  int mt  = rem >> 1;                 // 64 mt slots (mt-major within group)
  int nt  = ntg * 2 + (rem & 1);      // nt-minor within group
  int cnt = counts[e];
  if (mt * BM >= cnt) return;
  int rbase = base[e] + mt * BM;

  __shared__ unsigned short sA[DEPTH * BM * BK];
  __shared__ unsigned short sB[DEPTH * BN * BK];

  int tid = threadIdx.x;
  int wv = tid >> 6, lane = tid & 63;

  int r0 = tid >> 2,         kq0 = (tid & 3) ^ ((r0 >> 1) & 3);
  int r1 = (tid + 256) >> 2, kq1 = (tid & 3) ^ ((r1 >> 1) & 3);

  const unsigned short* aP0 = hid + (size_t)(rbase + r0) * F_DIM + kq0 * 8;
  const unsigned short* aP1 = hid + (size_t)(rbase + r1) * F_DIM + kq1 * 8;
  const unsigned short* wb = g_w2t + (size_t)e * H_DIM * F_DIM + (size_t)nt * BN * F_DIM;
  const unsigned short* bP0 = wb + (size_t)r0 * F_DIM + kq0 * 8;
  const unsigned short* bP1 = wb + (size_t)r1 * F_DIM + kq1 * 8;

  char* sAb = (char*)sA + wv * 1024;
  char* sBb = (char*)sB + wv * 1024;

  int wm = (wv >> 1) * 64, wn = (wv & 1) * 64;
  int lm = lane & 15, quad = lane >> 4;
  const unsigned short* aRd[4];
  const unsigned short* bRd[4];
#pragma unroll
  for (int mi = 0; mi < 4; mi++) {
    int R = wm + mi * 16 + lm;
    aRd[mi] = sA + (size_t)(4 * R + (quad ^ ((R >> 1) & 3))) * 8;
  }
#pragma unroll
  for (int ni = 0; ni < 4; ni++) {
    int R = wn + ni * 16 + lm;
    bRd[ni] = sB + (size_t)(4 * R + (quad ^ ((R >> 1) & 3))) * 8;
  }

  floatx4 acc[4][4];
#pragma unroll
  for (int mi = 0; mi < 4; mi++)
#pragma unroll
    for (int ni = 0; ni < 4; ni++)
      acc[mi][ni] = (floatx4){0.f, 0.f, 0.f, 0.f};

#pragma unroll
  for (int d = 0; d < DEPTH; d++) {
    async16(aP0, sAb + d * 8192); async16(aP1, sAb + d * 8192 + 4096);
    async16(bP0, sBb + d * 8192); async16(bP1, sBb + d * 8192 + 4096);
    aP0 += BK; aP1 += BK; bP0 += BK; bP1 += BK;
  }

  const int niter = F_DIM / BK;
  int bufc = 0;
  for (int i = 0; i < niter; i++) {
    asm volatile("s_waitcnt vmcnt(4)" ::: "memory");
    __builtin_amdgcn_sched_barrier(0);
    __builtin_amdgcn_s_barrier();            // B1: tile i ready
    __builtin_amdgcn_sched_barrier(0);

    int co = bufc * (BM * BK);
    short8 af[4], bfr[4];
#pragma unroll
    for (int mi = 0; mi < 4; mi++) af[mi] = *(const short8*)(aRd[mi] + co);
#pragma unroll
    for (int ni = 0; ni < 4; ni++) bfr[ni] = *(const short8*)(bRd[ni] + co);

    asm volatile("s_waitcnt lgkmcnt(0)" ::: "memory");
    __builtin_amdgcn_sched_barrier(0);
    __builtin_amdgcn_s_barrier();            // B2: tile i consumed
    __builtin_amdgcn_sched_barrier(0);

    async16(aP0, sAb + bufc * 8192); async16(aP1, sAb + bufc * 8192 + 4096);
    async16(bP0, sBb + bufc * 8192); async16(bP1, sBb + bufc * 8192 + 4096);
    if (i + DEPTH < niter - 1) { aP0 += BK; aP1 += BK; bP0 += BK; bP1 += BK; }

    __builtin_amdgcn_s_setprio(1);
#pragma unroll
    for (int mi = 0; mi < 4; mi++)
#pragma unroll
      for (int ni = 0; ni < 4; ni++)
        acc[mi][ni] = __builtin_amdgcn_mfma_f32_16x16x32_bf16(
            af[mi], bfr[ni], acc[mi][ni], 0, 0, 0);
    __builtin_amdgcn_s_setprio(0);

    bufc ^= 1;
  }
  asm volatile("s_waitcnt vmcnt(0)" ::: "memory");

  const float* b2e = b2 + (size_t)e * H_DIM;
#pragma unroll
  for (int mi = 0; mi < 4; mi++) {
#pragma unroll
    for (int r = 0; r < 4; r++) {
      int row = wm + mi * 16 + quad * 4 + r;
      if (mt * BM + row < cnt) {
        int prow = rbase + row;
        int tok = ptok[prow];
        float pw = pwt[prow];
        float* orow = out + (size_t)tok * H_DIM;
#pragma unroll
        for (int ni = 0; ni < 4; ni++) {
          int col = nt * BN + wn + ni * 16 + lm;
          atomicAdd(&orow[col], (acc[mi][ni][r] + b2e[col]) * pw);
        }
      }
    }
  }
}

extern "C" void kernel_launch(void* const* d_in, const int* in_sizes, int n_in,
                              void* d_out, int out_size, void* d_ws, size_t ws_size,
                              hipStream_t stream) {
  const float* x  = (const float*)d_in[0];
  const float* rw = (const float*)d_in[1];
  const float* w1 = (const float*)d_in[2];
  const float* b1 = (const float*)d_in[3];
  const float* w2 = (const float*)d_in[4];
  const float* b2 = (const float*)d_in[5];
  float* out = (float*)d_out;
  char* ws = (char*)d_ws;

  hipMemsetAsync(out, 0, (size_t)T_TOK * H_DIM * sizeof(float), stream);
  if (ws_size < WS_NEED) return;

  unsigned short* xb  = (unsigned short*)(ws + XB_OFF);
  unsigned short* hid = (unsigned short*)(ws + HID_OFF);
  int*   ptok   = (int*)(ws + PTOK_OFF);
  float* pw     = (float*)(ws + PW_OFF);
  int*   topi   = (int*)(ws + TOPI_OFF);
  float* topw   = (float*)(ws + TOPW_OFF);
  int*   counts = (int*)(ws + CNT_OFF);
  int*   base   = (int*)(ws + BASE_OFF);
  int*   cursor = (int*)(ws + CUR_OFF);

  hipMemsetAsync(ws + CNT_OFF, 0, 96, stream);

  wt_kernel<<<dim3(F_DIM / 64, H_DIM / 64, N_EXP), 256, 0, stream>>>(w1, H_DIM, F_DIM, 0);
  wt_kernel<<<dim3(H_DIM / 64, F_DIM / 64, N_EXP), 256, 0, stream>>>(w2, F_DIM, H_DIM, 1);
  router_kernel<<<T_TOK / 4, 256, 0, stream>>>(x, rw, xb, topi, topw);
  hist_kernel<<<64, 256, 0, stream>>>(topi, counts);
  scan_kernel<<<1, 64, 0, stream>>>(counts, base, cursor);
  build_kernel<<<T_TOK / 256, 256, 0, stream>>>(topi, topw, cursor, ptok, pw);
  gemm1_kernel<<<16384, 256, 0, stream>>>(xb, b1, hid, ptok, counts, base);
  gemm2_kernel<<<4096, 256, 0, stream>>>(hid, b2, ptok, pw, counts, base, out);
}